// Round 17
// baseline (92.286 us; speedup 1.0000x reference)
//
#include <hip/hip_runtime.h>
#include <hip/hip_bf16.h>
#include <math.h>

#define EPS 1e-8f

typedef __attribute__((ext_vector_type(2))) unsigned long ulongx2;
typedef __attribute__((ext_vector_type(4))) float floatx4;
typedef unsigned char uchar_t;

#define GPTR(p) ((const __attribute__((address_space(1))) void*)(p))
#define LPTR(p) ((__attribute__((address_space(3))) void*)(p))

__device__ __forceinline__ unsigned int pk4(float a, float b, float c, float d) {
  int v = __builtin_amdgcn_cvt_pk_fp8_f32(a, b, 0, false);
  v = __builtin_amdgcn_cvt_pk_fp8_f32(c, d, v, true);
  return (unsigned int)v;
}

// ---- kA: one block per 16-row group (2048 blocks, 15.4KB LDS -> 8 blk/CU
// = 32 waves/CU). Row norms (xx,rxn), fp8 convert -> fm blobs, per-block
// column sums via LDS ds_add -> ONE plain store to part[g][768]. No global
// atomics.
__global__ __launch_bounds__(256) void kA(const float* __restrict__ x,
    uchar_t* __restrict__ xbf8fm, float* __restrict__ part,
    float* __restrict__ xx, float* __restrict__ rxn) {
  const int g = blockIdx.x;            // group 0..2047 (16 rows each)
  const int t = threadIdx.x;
  const int wv = t >> 6, l = t & 63;
  __shared__ uchar_t xs[16][776];      // 12.4KB padded fp8 staging
  __shared__ float csumL[768];         // 3KB block column sums

  csumL[t] = 0.f; csumL[t + 256] = 0.f; csumL[t + 512] = 0.f;
  __syncthreads();

  float4 cs0 = {0,0,0,0}, cs1 = {0,0,0,0}, cs2 = {0,0,0,0};
#pragma unroll
  for (int rr = 0; rr < 4; ++rr) {
    const int r = wv * 4 + rr;         // local row 0..15
    const size_t base = ((size_t)g * 16 + r) * 768;
    const float* rp = x + base;
    float4 v0 = *(const float4*)(rp + l * 4);
    float4 v1 = *(const float4*)(rp + l * 4 + 256);
    float4 v2 = *(const float4*)(rp + l * 4 + 512);
    *(unsigned int*)&xs[r][l * 4]       = pk4(v0.x, v0.y, v0.z, v0.w);
    *(unsigned int*)&xs[r][l * 4 + 256] = pk4(v1.x, v1.y, v1.z, v1.w);
    *(unsigned int*)&xs[r][l * 4 + 512] = pk4(v2.x, v2.y, v2.z, v2.w);
    float rq = v0.x*v0.x + v0.y*v0.y + v0.z*v0.z + v0.w*v0.w
             + v1.x*v1.x + v1.y*v1.y + v1.z*v1.z + v1.w*v1.w
             + v2.x*v2.x + v2.y*v2.y + v2.z*v2.z + v2.w*v2.w;
    for (int o = 32; o; o >>= 1) rq += __shfl_xor(rq, o, 64);
    if (l == 0) {
      const int j = g * 16 + r;
      xx[j] = rq;
      rxn[j] = 1.0f / fmaxf(sqrtf(rq), EPS);
    }
    cs0.x += v0.x; cs0.y += v0.y; cs0.z += v0.z; cs0.w += v0.w;
    cs1.x += v1.x; cs1.y += v1.y; cs1.z += v1.z; cs1.w += v1.w;
    cs2.x += v2.x; cs2.y += v2.y; cs2.z += v2.z; cs2.w += v2.w;
  }
  // wave partial -> block sum in LDS (4-way max collision, cheap)
  atomicAdd(&csumL[l * 4 + 0], cs0.x); atomicAdd(&csumL[l * 4 + 1], cs0.y);
  atomicAdd(&csumL[l * 4 + 2], cs0.z); atomicAdd(&csumL[l * 4 + 3], cs0.w);
  atomicAdd(&csumL[l * 4 + 256], cs1.x); atomicAdd(&csumL[l * 4 + 257], cs1.y);
  atomicAdd(&csumL[l * 4 + 258], cs1.z); atomicAdd(&csumL[l * 4 + 259], cs1.w);
  atomicAdd(&csumL[l * 4 + 512], cs2.x); atomicAdd(&csumL[l * 4 + 513], cs2.y);
  atomicAdd(&csumL[l * 4 + 514], cs2.z); atomicAdd(&csumL[l * 4 + 515], cs2.w);
  __syncthreads();

  // one coalesced partial store (no global atomics)
  part[(size_t)g * 768 + t]       = csumL[t];
  part[(size_t)g * 768 + t + 256] = csumL[t + 256];
  part[(size_t)g * 768 + t + 512] = csumL[t + 512];

  // fm-layout fp8 write: this block owns group g (12 x 1KB blobs)
#pragma unroll
  for (int ksi = 0; ksi < 3; ++ksi) {
    const int ks = wv * 3 + ksi;
    const uchar_t* sp = &xs[l & 15][ks * 64 + (l >> 4) * 8];
    uint2 lo = *(const uint2*)sp;
    uint2 hi = *(const uint2*)(sp + 32);
    uint4 outv = {lo.x, lo.y, hi.x, hi.y};
    *(uint4*)(xbf8fm + (size_t)((g * 12 + ks) * 64 + l) * 16) = outv;
  }
}

// ---- kA2: 32 blocks x 16 speakers. Reduce 4 partials/speaker -> sums in
// LDS; ss/rcn; fp8 fm blobs for sums.
__global__ __launch_bounds__(256) void kA2(const float* __restrict__ part,
    uchar_t* __restrict__ sums8fm, float* __restrict__ ss,
    float* __restrict__ rcn, const float* __restrict__ wp) {
  const int g = blockIdx.x;            // 0..31 (16 speakers each)
  const int t = threadIdx.x;
  const int wv = t >> 6, l = t & 63;
  __shared__ float sums_l[16][772];    // ~49.4KB (stride 772: 16B-aligned, ~2-way)
  __shared__ float ssl[16];
  if (t < 16) ssl[t] = 0.f;

  float lss[16];
#pragma unroll
  for (int s = 0; s < 16; ++s) lss[s] = 0.f;
#pragma unroll
  for (int s = 0; s < 16; ++s) {
    const int n = g * 16 + s;
    const float* p0 = part + (size_t)(4 * n + 0) * 768;
    const float* p1 = part + (size_t)(4 * n + 1) * 768;
    const float* p2 = part + (size_t)(4 * n + 2) * 768;
    const float* p3 = part + (size_t)(4 * n + 3) * 768;
#pragma unroll
    for (int q = 0; q < 3; ++q) {
      const int c = t + q * 256;
      const float v = p0[c] + p1[c] + p2[c] + p3[c];
      sums_l[s][c] = v;
      lss[s] += v * v;
    }
  }
  __syncthreads();
#pragma unroll
  for (int s = 0; s < 16; ++s) {
    float v = lss[s];
    for (int o = 32; o; o >>= 1) v += __shfl_xor(v, o, 64);
    if (l == 0) atomicAdd(&ssl[s], v);
  }
  __syncthreads();
  if (t < 16) {
    const int n = g * 16 + t;
    const float v = ssl[t];
    ss[n] = v;
    rcn[n] = (*wp) / fmaxf(sqrtf(v), 64.f * EPS);   // w / (M * cn)
  }

  // fm conversion: wave wv -> K64-steps wv*3..wv*3+2
#pragma unroll
  for (int ksi = 0; ksi < 3; ++ksi) {
    const int ks = wv * 3 + ksi;
    const float* sp = &sums_l[l & 15][ks * 64 + (l >> 4) * 8];
    float4 a0 = *(const float4*)sp;
    float4 a1 = *(const float4*)(sp + 4);
    float4 b0 = *(const float4*)(sp + 32);
    float4 b1 = *(const float4*)(sp + 36);
    uint4 outv = { pk4(a0.x, a0.y, a0.z, a0.w), pk4(a1.x, a1.y, a1.z, a1.w),
                   pk4(b0.x, b0.y, b0.z, b0.w), pk4(b1.x, b1.y, b1.z, b1.w) };
    *(uint4*)(sums8fm + (size_t)((g * 12 + ks) * 64 + l) * 16) = outv;
  }
}

// ---- kC: fp8 GEMM, 256n x 256j tile, 256 blocks (1/CU), 8 waves.
// fm-layout operands -> gload_lds reads contiguous 1KB blobs (L2-linear).
// 12 K64-steps, 4 x 32KB buffers, counted vmcnt. Fused epilogue:
// exp + colsum atomics + diagonal sx extraction (consistent cancellation).
__global__ __launch_bounds__(512, 2) void kC(const uchar_t* __restrict__ xbf8fm,
    const uchar_t* __restrict__ sums8fm, const float* __restrict__ rcn,
    const float* __restrict__ rxn, float* __restrict__ colsum,
    float* __restrict__ sdiag_dot, const float* __restrict__ bp) {
  __shared__ uchar_t lds[4][32768];    // [A blobs 0..15 | B blobs 0..15] x 1KB
  const int b = blockIdx.x;
  const int xcd = b & 7;
  const int inner = b >> 3;
  const int nt = inner & 1;
  const int jt = xcd + ((inner >> 1) << 3);
  const int n0 = nt * 256, j0 = jt * 256;
  const int t = threadIdx.x, wv = t >> 6, l = t & 63;
  const int wm = wv >> 2, wj = wv & 3;
  const int gA0 = n0 / 16, gB0 = j0 / 16;

#define STAGE(KS_, BUF_) {                                                     \
    const int fb0_ = wv * 2, fb1_ = wv * 2 + 1;                                \
    __builtin_amdgcn_global_load_lds(                                          \
        GPTR(sums8fm + (size_t)(((gA0 + fb0_) * 12 + (KS_)) * 64 + l) * 16),   \
        LPTR(&lds[BUF_][fb0_ * 1024]), 16, 0, 0);                              \
    __builtin_amdgcn_global_load_lds(                                          \
        GPTR(sums8fm + (size_t)(((gA0 + fb1_) * 12 + (KS_)) * 64 + l) * 16),   \
        LPTR(&lds[BUF_][fb1_ * 1024]), 16, 0, 0);                              \
    __builtin_amdgcn_global_load_lds(                                          \
        GPTR(xbf8fm + (size_t)(((gB0 + fb0_) * 12 + (KS_)) * 64 + l) * 16),    \
        LPTR(&lds[BUF_][16384 + fb0_ * 1024]), 16, 0, 0);                      \
    __builtin_amdgcn_global_load_lds(                                          \
        GPTR(xbf8fm + (size_t)(((gB0 + fb1_) * 12 + (KS_)) * 64 + l) * 16),    \
        LPTR(&lds[BUF_][16384 + fb1_ * 1024]), 16, 0, 0);                      \
  }

  floatx4 acc[8][4];
#pragma unroll
  for (int mi = 0; mi < 8; ++mi)
#pragma unroll
    for (int ni = 0; ni < 4; ++ni) acc[mi][ni] = (floatx4){0.f, 0.f, 0.f, 0.f};

  STAGE(0, 0)
  STAGE(1, 1)
  STAGE(2, 2)                          // 12 loads/thread outstanding

  for (int kb = 0; kb < 12; ++kb) {
    if (kb < 10)       { asm volatile("s_waitcnt vmcnt(8)" ::: "memory"); }
    else if (kb == 10) { asm volatile("s_waitcnt vmcnt(4)" ::: "memory"); }
    else               { asm volatile("s_waitcnt vmcnt(0)" ::: "memory"); }
    __builtin_amdgcn_s_barrier();
    __builtin_amdgcn_sched_barrier(0);   // keep ds_reads below the barrier
    const int cb = kb & 3, sb = (kb + 3) & 3;

    ulongx2 af[8], bf[4];
#pragma unroll
    for (int ni = 0; ni < 4; ++ni)
      bf[ni] = *(const ulongx2*)&lds[cb][16384 + (wj * 4 + ni) * 1024 + l * 16];
#pragma unroll
    for (int mi = 0; mi < 8; ++mi)
      af[mi] = *(const ulongx2*)&lds[cb][(wm * 8 + mi) * 1024 + l * 16];
    if (kb + 3 < 12) STAGE(kb + 3, sb)
    __builtin_amdgcn_s_setprio(1);
#pragma unroll
    for (int mi = 0; mi < 8; ++mi)
#pragma unroll
      for (int ni = 0; ni < 4; ++ni) {
        acc[mi][ni] = __builtin_amdgcn_mfma_f32_16x16x32_fp8_fp8(
            (long)af[mi].x, (long)bf[ni].x, acc[mi][ni], 0, 0, 0);
        acc[mi][ni] = __builtin_amdgcn_mfma_f32_16x16x32_fp8_fp8(
            (long)af[mi].y, (long)bf[ni].y, acc[mi][ni], 0, 0, 0);
      }
    __builtin_amdgcn_s_setprio(0);
  }

  // ---- epilogue: S = acc * rcn[n] * rxn[j] + b ; colsum += exp(S); diag sx.
  const float bb = *bp;
  float rxv[4], p[4] = {0.f, 0.f, 0.f, 0.f};
#pragma unroll
  for (int ni = 0; ni < 4; ++ni)
    rxv[ni] = rxn[j0 + wj * 64 + ni * 16 + (l & 15)];
  const bool diagblk = (nt == (jt >> 6));

#pragma unroll
  for (int mi = 0; mi < 8; ++mi) {
    float4 rr = *(const float4*)&rcn[n0 + wm * 128 + mi * 16 + ((l >> 4) << 2)];
    const float rc[4] = {rr.x, rr.y, rr.z, rr.w};
#pragma unroll
    for (int ni = 0; ni < 4; ++ni) {
      floatx4 a = acc[mi][ni];
#pragma unroll
      for (int q = 0; q < 4; ++q)
        p[ni] += __expf(a[q] * rc[q] * rxv[ni] + bb);
      if (diagblk) {
        const int jg = j0 + wj * 64 + ni * 16 + (l & 15);
#pragma unroll
        for (int q = 0; q < 4; ++q) {
          const int mg = n0 + wm * 128 + mi * 16 + ((l >> 4) << 2) + q;
          if (mg == (jg >> 6)) sdiag_dot[jg] = a[q];
        }
      }
    }
  }
#pragma unroll
  for (int ni = 0; ni < 4; ++ni) {
    p[ni] += __shfl_xor(p[ni], 16, 64);
    p[ni] += __shfl_xor(p[ni], 32, 64);
  }
  if (l < 16) {
#pragma unroll
    for (int ni = 0; ni < 4; ++ni)
      atomicAdd(&colsum[j0 + wj * 64 + ni * 16 + l], p[ni]);
  }
}

// ---- kD: per-sample loss from colsum + diagonal dot, reduce to scalar -----
__global__ __launch_bounds__(256) void kD(const float* __restrict__ colsum,
    const float* __restrict__ sdiag_dot, const float* __restrict__ xx,
    const float* __restrict__ ss, const float* __restrict__ rcn,
    const float* __restrict__ wp, const float* __restrict__ bp,
    float* __restrict__ out) {
  const int j = blockIdx.x * 256 + threadIdx.x;
  const int i = j >> 6;
  const float ww = *wp, bb = *bp;
  const float sx = sdiag_dot[j];
  const float xxv = xx[j];
  const float xn = fmaxf(sqrtf(xxv), EPS);
  const float rx = 1.0f / xn;
  const float sd = sx * rcn[i] * rx + bb;                         // S_diag
  const float exn = sqrtf(fmaxf(ss[i] - 2.f * sx + xxv, 0.f)) * (1.f / 63.f);
  const float edot = (sx - xxv) * (1.f / 63.f);
  const float sm = ww * edot / (fmaxf(exn, EPS) * xn) + bb;       // S_same
  const float tot = colsum[j] - __expf(sd) + __expf(sm);
  float L = -sm + logf(fmaxf(tot, 1e-30f));
  for (int o = 32; o; o >>= 1) L += __shfl_xor(L, o, 64);
  __shared__ float red[4];
  if ((threadIdx.x & 63) == 0) red[threadIdx.x >> 6] = L;
  __syncthreads();
  if (threadIdx.x == 0) atomicAdd(out, red[0] + red[1] + red[2] + red[3]);
}

extern "C" void kernel_launch(void* const* d_in, const int* in_sizes, int n_in,
                              void* d_out, int out_size, void* d_ws, size_t ws_size,
                              hipStream_t stream) {
  const float* x  = (const float*)d_in[0];
  const float* wp = (const float*)d_in[1];
  const float* bp = (const float*)d_in[2];
  float* out = (float*)d_out;

  // ws layout (float offsets):
  float* fws = (float*)d_ws;
  float* ss        = fws;              // 512
  float* rcn       = fws + 512;        // 512
  float* xx        = fws + 1024;       // 32768
  float* rxn       = fws + 33792;      // 32768
  float* colsum    = fws + 66560;      // 32768
  float* sdiag_dot = fws + 99328;      // 32768
  float* part      = fws + 132096;     // 1572864 (2048 x 768)
  uchar_t* sums8fm = (uchar_t*)(fws + 1704960);  // 393216 bytes
  uchar_t* xbf8fm  = (uchar_t*)(fws + 1803264);  // 25165824 bytes
  // total ~= 32.4 MiB

  hipMemsetAsync(colsum, 0, 32768 * sizeof(float), stream);
  hipMemsetAsync(out, 0, sizeof(float), stream);

  kA<<<2048, 256, 0, stream>>>(x, xbf8fm, part, xx, rxn);
  kA2<<<32, 256, 0, stream>>>(part, sums8fm, ss, rcn, wp);
  kC<<<256, 512, 0, stream>>>(xbf8fm, sums8fm, rcn, rxn, colsum, sdiag_dot, bp);
  kD<<<128, 256, 0, stream>>>(colsum, sdiag_dot, xx, ss, rcn, wp, bp, out);
}

// Round 18
// 64.869 us; speedup vs baseline: 1.4227x; 1.4227x over previous
//
#include <hip/hip_runtime.h>
#include <hip/hip_bf16.h>
#include <math.h>

#define EPS 1e-8f

typedef __attribute__((ext_vector_type(2))) unsigned long ulongx2;
typedef __attribute__((ext_vector_type(4))) float floatx4;
typedef unsigned char uchar_t;

#define GPTR(p) ((const __attribute__((address_space(1))) void*)(p))
#define LPTR(p) ((__attribute__((address_space(3))) void*)(p))

__device__ __forceinline__ unsigned int pk4(float a, float b, float c, float d) {
  int v = __builtin_amdgcn_cvt_pk_fp8_f32(a, b, 0, false);
  v = __builtin_amdgcn_cvt_pk_fp8_f32(c, d, v, true);
  return (unsigned int)v;
}

// ---- kA: one block per 16-row group (2048 blocks, 24.4KB LDS -> 6 blk/CU
// = 24 waves/CU). ALL 12 float4 loads batched up-front (forces ~90 VGPR,
// 12 loads in flight). No atomics: column partials via plain LDS stores +
// tree add -> part[g][768]. fp8 transpose via padded xs[16][776].
__global__ __launch_bounds__(256) void kA(const float* __restrict__ x,
    uchar_t* __restrict__ xbf8fm, float* __restrict__ part,
    float* __restrict__ xx, float* __restrict__ rxn) {
  const int g = blockIdx.x;            // group 0..2047 (16 rows each)
  const int t = threadIdx.x;
  const int wv = t >> 6, l = t & 63;
  __shared__ uchar_t xs[16][776];      // 12.4KB padded fp8 staging
  __shared__ float csum[4][768];       // 12KB wave partials

  // ---- batched loads: 12 independent float4s in flight
  float4 v[4][3];
#pragma unroll
  for (int rr = 0; rr < 4; ++rr) {
    const float* rp = x + ((size_t)g * 16 + wv * 4 + rr) * 768 + l * 4;
#pragma unroll
    for (int q = 0; q < 3; ++q)
      v[rr][q] = *(const float4*)(rp + q * 256);
  }

  // ---- process: fp8 convert -> xs, row norms, column partials in regs
  float4 cs[3] = {{0,0,0,0},{0,0,0,0},{0,0,0,0}};
#pragma unroll
  for (int rr = 0; rr < 4; ++rr) {
    const int r = wv * 4 + rr;
    float rq = 0.f;
#pragma unroll
    for (int q = 0; q < 3; ++q) {
      const float4 u = v[rr][q];
      *(unsigned int*)&xs[r][l * 4 + q * 256] = pk4(u.x, u.y, u.z, u.w);
      rq += u.x*u.x + u.y*u.y + u.z*u.z + u.w*u.w;
      cs[q].x += u.x; cs[q].y += u.y; cs[q].z += u.z; cs[q].w += u.w;
    }
    for (int o = 32; o; o >>= 1) rq += __shfl_xor(rq, o, 64);
    if (l == 0) {
      const int j = g * 16 + r;
      xx[j] = rq;
      rxn[j] = 1.0f / fmaxf(sqrtf(rq), EPS);
    }
  }
#pragma unroll
  for (int q = 0; q < 3; ++q)
    *(float4*)&csum[wv][l * 4 + q * 256] = cs[q];
  __syncthreads();

  // ---- column reduce over 4 waves -> one coalesced partial store
#pragma unroll
  for (int q = 0; q < 3; ++q) {
    const int c = t + q * 256;
    part[(size_t)g * 768 + c] = csum[0][c] + csum[1][c] + csum[2][c] + csum[3][c];
  }

  // ---- fm-layout fp8 write: this block owns group g (12 x 1KB blobs)
#pragma unroll
  for (int ksi = 0; ksi < 3; ++ksi) {
    const int ks = wv * 3 + ksi;
    const uchar_t* sp = &xs[l & 15][ks * 64 + (l >> 4) * 8];
    uint2 lo = *(const uint2*)sp;
    uint2 hi = *(const uint2*)(sp + 32);
    uint4 outv = {lo.x, lo.y, hi.x, hi.y};
    *(uint4*)(xbf8fm + (size_t)((g * 12 + ks) * 64 + l) * 16) = outv;
  }
}

// ---- kA2: 32 blocks x 16 speakers. Reduce 4 partials/speaker -> sums in
// LDS; ss/rcn; fp8 fm blobs for sums.
__global__ __launch_bounds__(256) void kA2(const float* __restrict__ part,
    uchar_t* __restrict__ sums8fm, float* __restrict__ ss,
    float* __restrict__ rcn, const float* __restrict__ wp) {
  const int g = blockIdx.x;            // 0..31 (16 speakers each)
  const int t = threadIdx.x;
  const int wv = t >> 6, l = t & 63;
  __shared__ float sums_l[16][772];    // ~49.4KB (stride 772: 16B-aligned)
  __shared__ float ssl[16];
  if (t < 16) ssl[t] = 0.f;

  float lss[16];
#pragma unroll
  for (int s = 0; s < 16; ++s) lss[s] = 0.f;
#pragma unroll
  for (int s = 0; s < 16; ++s) {
    const int n = g * 16 + s;
    const float* p0 = part + (size_t)(4 * n + 0) * 768;
    const float* p1 = part + (size_t)(4 * n + 1) * 768;
    const float* p2 = part + (size_t)(4 * n + 2) * 768;
    const float* p3 = part + (size_t)(4 * n + 3) * 768;
#pragma unroll
    for (int q = 0; q < 3; ++q) {
      const int c = t + q * 256;
      const float v = p0[c] + p1[c] + p2[c] + p3[c];
      sums_l[s][c] = v;
      lss[s] += v * v;
    }
  }
  __syncthreads();
#pragma unroll
  for (int s = 0; s < 16; ++s) {
    float v = lss[s];
    for (int o = 32; o; o >>= 1) v += __shfl_xor(v, o, 64);
    if (l == 0) atomicAdd(&ssl[s], v);
  }
  __syncthreads();
  if (t < 16) {
    const int n = g * 16 + t;
    const float v = ssl[t];
    ss[n] = v;
    rcn[n] = (*wp) / fmaxf(sqrtf(v), 64.f * EPS);   // w / (M * cn)
  }

  // fm conversion: wave wv -> K64-steps wv*3..wv*3+2
#pragma unroll
  for (int ksi = 0; ksi < 3; ++ksi) {
    const int ks = wv * 3 + ksi;
    const float* sp = &sums_l[l & 15][ks * 64 + (l >> 4) * 8];
    float4 a0 = *(const float4*)sp;
    float4 a1 = *(const float4*)(sp + 4);
    float4 b0 = *(const float4*)(sp + 32);
    float4 b1 = *(const float4*)(sp + 36);
    uint4 outv = { pk4(a0.x, a0.y, a0.z, a0.w), pk4(a1.x, a1.y, a1.z, a1.w),
                   pk4(b0.x, b0.y, b0.z, b0.w), pk4(b1.x, b1.y, b1.z, b1.w) };
    *(uint4*)(sums8fm + (size_t)((g * 12 + ks) * 64 + l) * 16) = outv;
  }
}

// ---- kC: fp8 GEMM, 256n x 256j tile, 256 blocks (1/CU), 8 waves.
// fm-layout operands -> gload_lds reads contiguous 1KB blobs (L2-linear).
// 12 K64-steps, 4 x 32KB buffers, counted vmcnt. Fused epilogue:
// exp + colsum atomics + diagonal sx extraction (consistent cancellation).
__global__ __launch_bounds__(512, 2) void kC(const uchar_t* __restrict__ xbf8fm,
    const uchar_t* __restrict__ sums8fm, const float* __restrict__ rcn,
    const float* __restrict__ rxn, float* __restrict__ colsum,
    float* __restrict__ sdiag_dot, const float* __restrict__ bp) {
  __shared__ uchar_t lds[4][32768];    // [A blobs 0..15 | B blobs 0..15] x 1KB
  const int b = blockIdx.x;
  const int xcd = b & 7;
  const int inner = b >> 3;
  const int nt = inner & 1;
  const int jt = xcd + ((inner >> 1) << 3);
  const int n0 = nt * 256, j0 = jt * 256;
  const int t = threadIdx.x, wv = t >> 6, l = t & 63;
  const int wm = wv >> 2, wj = wv & 3;
  const int gA0 = n0 / 16, gB0 = j0 / 16;

#define STAGE(KS_, BUF_) {                                                     \
    const int fb0_ = wv * 2, fb1_ = wv * 2 + 1;                                \
    __builtin_amdgcn_global_load_lds(                                          \
        GPTR(sums8fm + (size_t)(((gA0 + fb0_) * 12 + (KS_)) * 64 + l) * 16),   \
        LPTR(&lds[BUF_][fb0_ * 1024]), 16, 0, 0);                              \
    __builtin_amdgcn_global_load_lds(                                          \
        GPTR(sums8fm + (size_t)(((gA0 + fb1_) * 12 + (KS_)) * 64 + l) * 16),   \
        LPTR(&lds[BUF_][fb1_ * 1024]), 16, 0, 0);                              \
    __builtin_amdgcn_global_load_lds(                                          \
        GPTR(xbf8fm + (size_t)(((gB0 + fb0_) * 12 + (KS_)) * 64 + l) * 16),    \
        LPTR(&lds[BUF_][16384 + fb0_ * 1024]), 16, 0, 0);                      \
    __builtin_amdgcn_global_load_lds(                                          \
        GPTR(xbf8fm + (size_t)(((gB0 + fb1_) * 12 + (KS_)) * 64 + l) * 16),    \
        LPTR(&lds[BUF_][16384 + fb1_ * 1024]), 16, 0, 0);                      \
  }

  floatx4 acc[8][4];
#pragma unroll
  for (int mi = 0; mi < 8; ++mi)
#pragma unroll
    for (int ni = 0; ni < 4; ++ni) acc[mi][ni] = (floatx4){0.f, 0.f, 0.f, 0.f};

  STAGE(0, 0)
  STAGE(1, 1)
  STAGE(2, 2)                          // 12 loads/thread outstanding

  for (int kb = 0; kb < 12; ++kb) {
    if (kb < 10)       { asm volatile("s_waitcnt vmcnt(8)" ::: "memory"); }
    else if (kb == 10) { asm volatile("s_waitcnt vmcnt(4)" ::: "memory"); }
    else               { asm volatile("s_waitcnt vmcnt(0)" ::: "memory"); }
    __builtin_amdgcn_s_barrier();
    __builtin_amdgcn_sched_barrier(0);   // keep ds_reads below the barrier
    const int cb = kb & 3, sb = (kb + 3) & 3;

    ulongx2 af[8], bf[4];
#pragma unroll
    for (int ni = 0; ni < 4; ++ni)
      bf[ni] = *(const ulongx2*)&lds[cb][16384 + (wj * 4 + ni) * 1024 + l * 16];
#pragma unroll
    for (int mi = 0; mi < 8; ++mi)
      af[mi] = *(const ulongx2*)&lds[cb][(wm * 8 + mi) * 1024 + l * 16];
    if (kb + 3 < 12) STAGE(kb + 3, sb)
    __builtin_amdgcn_s_setprio(1);
#pragma unroll
    for (int mi = 0; mi < 8; ++mi)
#pragma unroll
      for (int ni = 0; ni < 4; ++ni) {
        acc[mi][ni] = __builtin_amdgcn_mfma_f32_16x16x32_fp8_fp8(
            (long)af[mi].x, (long)bf[ni].x, acc[mi][ni], 0, 0, 0);
        acc[mi][ni] = __builtin_amdgcn_mfma_f32_16x16x32_fp8_fp8(
            (long)af[mi].y, (long)bf[ni].y, acc[mi][ni], 0, 0, 0);
      }
    __builtin_amdgcn_s_setprio(0);
  }

  // ---- epilogue: S = acc * rcn[n] * rxn[j] + b ; colsum += exp(S); diag sx.
  const float bb = *bp;
  float rxv[4], p[4] = {0.f, 0.f, 0.f, 0.f};
#pragma unroll
  for (int ni = 0; ni < 4; ++ni)
    rxv[ni] = rxn[j0 + wj * 64 + ni * 16 + (l & 15)];
  const bool diagblk = (nt == (jt >> 6));

#pragma unroll
  for (int mi = 0; mi < 8; ++mi) {
    float4 rr = *(const float4*)&rcn[n0 + wm * 128 + mi * 16 + ((l >> 4) << 2)];
    const float rc[4] = {rr.x, rr.y, rr.z, rr.w};
#pragma unroll
    for (int ni = 0; ni < 4; ++ni) {
      floatx4 a = acc[mi][ni];
#pragma unroll
      for (int q = 0; q < 4; ++q)
        p[ni] += __expf(a[q] * rc[q] * rxv[ni] + bb);
      if (diagblk) {
        const int jg = j0 + wj * 64 + ni * 16 + (l & 15);
#pragma unroll
        for (int q = 0; q < 4; ++q) {
          const int mg = n0 + wm * 128 + mi * 16 + ((l >> 4) << 2) + q;
          if (mg == (jg >> 6)) sdiag_dot[jg] = a[q];
        }
      }
    }
  }
#pragma unroll
  for (int ni = 0; ni < 4; ++ni) {
    p[ni] += __shfl_xor(p[ni], 16, 64);
    p[ni] += __shfl_xor(p[ni], 32, 64);
  }
  if (l < 16) {
#pragma unroll
    for (int ni = 0; ni < 4; ++ni)
      atomicAdd(&colsum[j0 + wj * 64 + ni * 16 + l], p[ni]);
  }
}

// ---- kD: per-sample loss from colsum + diagonal dot, reduce to scalar -----
__global__ __launch_bounds__(256) void kD(const float* __restrict__ colsum,
    const float* __restrict__ sdiag_dot, const float* __restrict__ xx,
    const float* __restrict__ ss, const float* __restrict__ rcn,
    const float* __restrict__ wp, const float* __restrict__ bp,
    float* __restrict__ out) {
  const int j = blockIdx.x * 256 + threadIdx.x;
  const int i = j >> 6;
  const float ww = *wp, bb = *bp;
  const float sx = sdiag_dot[j];
  const float xxv = xx[j];
  const float xn = fmaxf(sqrtf(xxv), EPS);
  const float rx = 1.0f / xn;
  const float sd = sx * rcn[i] * rx + bb;                         // S_diag
  const float exn = sqrtf(fmaxf(ss[i] - 2.f * sx + xxv, 0.f)) * (1.f / 63.f);
  const float edot = (sx - xxv) * (1.f / 63.f);
  const float sm = ww * edot / (fmaxf(exn, EPS) * xn) + bb;       // S_same
  const float tot = colsum[j] - __expf(sd) + __expf(sm);
  float L = -sm + logf(fmaxf(tot, 1e-30f));
  for (int o = 32; o; o >>= 1) L += __shfl_xor(L, o, 64);
  __shared__ float red[4];
  if ((threadIdx.x & 63) == 0) red[threadIdx.x >> 6] = L;
  __syncthreads();
  if (threadIdx.x == 0) atomicAdd(out, red[0] + red[1] + red[2] + red[3]);
}

extern "C" void kernel_launch(void* const* d_in, const int* in_sizes, int n_in,
                              void* d_out, int out_size, void* d_ws, size_t ws_size,
                              hipStream_t stream) {
  const float* x  = (const float*)d_in[0];
  const float* wp = (const float*)d_in[1];
  const float* bp = (const float*)d_in[2];
  float* out = (float*)d_out;

  // ws layout (float offsets):
  float* fws = (float*)d_ws;
  float* ss        = fws;              // 512
  float* rcn       = fws + 512;        // 512
  float* xx        = fws + 1024;       // 32768
  float* rxn       = fws + 33792;      // 32768
  float* colsum    = fws + 66560;      // 32768
  float* sdiag_dot = fws + 99328;      // 32768
  float* part      = fws + 132096;     // 1572864 (2048 x 768)
  uchar_t* sums8fm = (uchar_t*)(fws + 1704960);  // 393216 bytes
  uchar_t* xbf8fm  = (uchar_t*)(fws + 1803264);  // 25165824 bytes
  // total ~= 32.4 MiB

  hipMemsetAsync(colsum, 0, 32768 * sizeof(float), stream);
  hipMemsetAsync(out, 0, sizeof(float), stream);

  kA<<<2048, 256, 0, stream>>>(x, xbf8fm, part, xx, rxn);
  kA2<<<32, 256, 0, stream>>>(part, sums8fm, ss, rcn, wp);
  kC<<<256, 512, 0, stream>>>(xbf8fm, sums8fm, rcn, rxn, colsum, sdiag_dot, bp);
  kD<<<128, 256, 0, stream>>>(colsum, sdiag_dot, xx, ss, rcn, wp, bp, out);
}

// Round 19
// 52.606 us; speedup vs baseline: 1.7543x; 1.2331x over previous
//
#include <hip/hip_runtime.h>
#include <hip/hip_bf16.h>
#include <math.h>

#define EPS 1e-8f

typedef __attribute__((ext_vector_type(2))) unsigned long ulongx2;
typedef __attribute__((ext_vector_type(4))) float floatx4;
typedef unsigned char uchar_t;

#define GPTR(p) ((const __attribute__((address_space(1))) void*)(p))
#define LPTR(p) ((__attribute__((address_space(3))) void*)(p))

__device__ __forceinline__ unsigned int pk4(float a, float b, float c, float d) {
  int v = __builtin_amdgcn_cvt_pk_fp8_f32(a, b, 0, false);
  v = __builtin_amdgcn_cvt_pk_fp8_f32(c, d, v, true);
  return (unsigned int)v;
}

// ---- kA: one speaker per block (512 blocks, 61.7KB LDS -> 2 blk/CU).
// R15 structure + 4-row LOAD BATCHING (12 independent float4s in flight).
// col sums -> sums_f32/ss/rcn; row norms -> xx/rxn; fp8 fm blobs.
__global__ __launch_bounds__(256) void kA(const float* __restrict__ x,
    uchar_t* __restrict__ xbf8fm, float* __restrict__ sums_f32,
    float* __restrict__ ss, float* __restrict__ rcn,
    float* __restrict__ xx, float* __restrict__ rxn,
    const float* __restrict__ wp) {
  const int n = blockIdx.x;
  const int t = threadIdx.x;
  const int wv = t >> 6, l = t & 63;
  __shared__ uchar_t xs[4][16][776];   // 49.7KB padded fp8 staging
  __shared__ float csum[4][768];       // 12KB
  float4 cs[3] = {{0,0,0,0},{0,0,0,0},{0,0,0,0}};

  for (int c4 = 0; c4 < 4; ++c4) {
    // batched loads: 12 independent float4s before any processing
    float4 v[4][3];
#pragma unroll
    for (int rr = 0; rr < 4; ++rr) {
      const int r = wv * 16 + c4 * 4 + rr;
      const float* rp = x + ((size_t)n * 64 + r) * 768 + l * 4;
#pragma unroll
      for (int q = 0; q < 3; ++q) v[rr][q] = *(const float4*)(rp + q * 256);
    }
    // process
#pragma unroll
    for (int rr = 0; rr < 4; ++rr) {
      const int r = c4 * 4 + rr;       // local row 0..15
      float rq = 0.f;
#pragma unroll
      for (int q = 0; q < 3; ++q) {
        const float4 u = v[rr][q];
        *(unsigned int*)&xs[wv][r][l * 4 + q * 256] = pk4(u.x, u.y, u.z, u.w);
        rq += u.x*u.x + u.y*u.y + u.z*u.z + u.w*u.w;
        cs[q].x += u.x; cs[q].y += u.y; cs[q].z += u.z; cs[q].w += u.w;
      }
      for (int o = 32; o; o >>= 1) rq += __shfl_xor(rq, o, 64);
      if (l == 0) {
        const int j = n * 64 + wv * 16 + r - wv * 16 + wv * 16;  // = n*64 + wv*16 + (c4*4+rr)
        const int jj = n * 64 + wv * 16 + c4 * 4 + rr;
        xx[jj] = rq;
        rxn[jj] = 1.0f / fmaxf(sqrtf(rq), EPS);
        (void)j;
      }
    }
  }
#pragma unroll
  for (int q = 0; q < 3; ++q)
    *(float4*)&csum[wv][l * 4 + q * 256] = cs[q];
  __syncthreads();

  float lss = 0.f;
#pragma unroll
  for (int q = 0; q < 3; ++q) {
    const int c = t + q * 256;
    const float s = csum[0][c] + csum[1][c] + csum[2][c] + csum[3][c];
    sums_f32[(size_t)n * 768 + c] = s;
    lss += s * s;
  }
  for (int o = 32; o; o >>= 1) lss += __shfl_xor(lss, o, 64);
  __syncthreads();
  if (l == 0) csum[1][wv] = lss;
  __syncthreads();
  if (t == 0) {
    const float vv = csum[1][0] + csum[1][1] + csum[1][2] + csum[1][3];
    ss[n] = vv;
    rcn[n] = (*wp) / fmaxf(sqrtf(vv), 64.f * EPS);   // w / (M * cn)
  }

  // fm-layout fp8 write: wave wv owns group g = n*4 + wv (12 x 1KB blobs)
  {
    const int g = n * 4 + wv;
#pragma unroll
    for (int ks = 0; ks < 12; ++ks) {
      const uchar_t* sp = &xs[wv][l & 15][ks * 64 + (l >> 4) * 8];
      uint2 lo = *(const uint2*)sp;
      uint2 hi = *(const uint2*)(sp + 32);
      uint4 outv = {lo.x, lo.y, hi.x, hi.y};
      *(uint4*)(xbf8fm + (size_t)((g * 12 + ks) * 64 + l) * 16) = outv;
    }
  }
}

// ---- kA2: sums_f32 -> fp8 fm layout (32 groups x 12 ks x 1KB). Tiny.
__global__ __launch_bounds__(256) void kA2(const float* __restrict__ sums_f32,
    uchar_t* __restrict__ sums8fm) {
  const int g = blockIdx.x;
  const int wv = threadIdx.x >> 6, l = threadIdx.x & 63;
#pragma unroll
  for (int ksi = 0; ksi < 3; ++ksi) {
    const int ks = wv * 3 + ksi;
    const float* sp = sums_f32 + (size_t)(g * 16 + (l & 15)) * 768
                      + ks * 64 + (l >> 4) * 8;
    float4 a0 = *(const float4*)sp;
    float4 a1 = *(const float4*)(sp + 4);
    float4 b0 = *(const float4*)(sp + 32);
    float4 b1 = *(const float4*)(sp + 36);
    uint4 outv = { pk4(a0.x, a0.y, a0.z, a0.w), pk4(a1.x, a1.y, a1.z, a1.w),
                   pk4(b0.x, b0.y, b0.z, b0.w), pk4(b1.x, b1.y, b1.z, b1.w) };
    *(uint4*)(sums8fm + (size_t)((g * 12 + ks) * 64 + l) * 16) = outv;
  }
}

// ---- kC: fp8 GEMM, 256n x 256j tile, 256 blocks (1/CU), 8 waves.
// Identical to R15's verified kernel EXCEPT: colsum atomics -> plain
// stores into colsum_part[4][32768] (slot = nt*2+wm; unique writer).
__global__ __launch_bounds__(512, 2) void kC(const uchar_t* __restrict__ xbf8fm,
    const uchar_t* __restrict__ sums8fm, const float* __restrict__ rcn,
    const float* __restrict__ rxn, float* __restrict__ colsum_part,
    float* __restrict__ sdiag_dot, const float* __restrict__ bp) {
  __shared__ uchar_t lds[4][32768];    // [A blobs 0..15 | B blobs 0..15] x 1KB
  const int b = blockIdx.x;
  const int xcd = b & 7;
  const int inner = b >> 3;
  const int nt = inner & 1;
  const int jt = xcd + ((inner >> 1) << 3);
  const int n0 = nt * 256, j0 = jt * 256;
  const int t = threadIdx.x, wv = t >> 6, l = t & 63;
  const int wm = wv >> 2, wj = wv & 3;
  const int gA0 = n0 / 16, gB0 = j0 / 16;

#define STAGE(KS_, BUF_) {                                                     \
    const int fb0_ = wv * 2, fb1_ = wv * 2 + 1;                                \
    __builtin_amdgcn_global_load_lds(                                          \
        GPTR(sums8fm + (size_t)(((gA0 + fb0_) * 12 + (KS_)) * 64 + l) * 16),   \
        LPTR(&lds[BUF_][fb0_ * 1024]), 16, 0, 0);                              \
    __builtin_amdgcn_global_load_lds(                                          \
        GPTR(sums8fm + (size_t)(((gA0 + fb1_) * 12 + (KS_)) * 64 + l) * 16),   \
        LPTR(&lds[BUF_][fb1_ * 1024]), 16, 0, 0);                              \
    __builtin_amdgcn_global_load_lds(                                          \
        GPTR(xbf8fm + (size_t)(((gB0 + fb0_) * 12 + (KS_)) * 64 + l) * 16),    \
        LPTR(&lds[BUF_][16384 + fb0_ * 1024]), 16, 0, 0);                      \
    __builtin_amdgcn_global_load_lds(                                          \
        GPTR(xbf8fm + (size_t)(((gB0 + fb1_) * 12 + (KS_)) * 64 + l) * 16),    \
        LPTR(&lds[BUF_][16384 + fb1_ * 1024]), 16, 0, 0);                      \
  }

  floatx4 acc[8][4];
#pragma unroll
  for (int mi = 0; mi < 8; ++mi)
#pragma unroll
    for (int ni = 0; ni < 4; ++ni) acc[mi][ni] = (floatx4){0.f, 0.f, 0.f, 0.f};

  STAGE(0, 0)
  STAGE(1, 1)
  STAGE(2, 2)                          // 12 loads/thread outstanding

  for (int kb = 0; kb < 12; ++kb) {
    if (kb < 10)       { asm volatile("s_waitcnt vmcnt(8)" ::: "memory"); }
    else if (kb == 10) { asm volatile("s_waitcnt vmcnt(4)" ::: "memory"); }
    else               { asm volatile("s_waitcnt vmcnt(0)" ::: "memory"); }
    __builtin_amdgcn_s_barrier();
    __builtin_amdgcn_sched_barrier(0);   // keep ds_reads below the barrier
    const int cb = kb & 3, sb = (kb + 3) & 3;

    ulongx2 af[8], bf[4];
#pragma unroll
    for (int ni = 0; ni < 4; ++ni)
      bf[ni] = *(const ulongx2*)&lds[cb][16384 + (wj * 4 + ni) * 1024 + l * 16];
#pragma unroll
    for (int mi = 0; mi < 8; ++mi)
      af[mi] = *(const ulongx2*)&lds[cb][(wm * 8 + mi) * 1024 + l * 16];
    if (kb + 3 < 12) STAGE(kb + 3, sb)
    __builtin_amdgcn_s_setprio(1);
#pragma unroll
    for (int mi = 0; mi < 8; ++mi)
#pragma unroll
      for (int ni = 0; ni < 4; ++ni) {
        acc[mi][ni] = __builtin_amdgcn_mfma_f32_16x16x32_fp8_fp8(
            (long)af[mi].x, (long)bf[ni].x, acc[mi][ni], 0, 0, 0);
        acc[mi][ni] = __builtin_amdgcn_mfma_f32_16x16x32_fp8_fp8(
            (long)af[mi].y, (long)bf[ni].y, acc[mi][ni], 0, 0, 0);
      }
    __builtin_amdgcn_s_setprio(0);
  }

  // ---- epilogue: S = acc * rcn[n] * rxn[j] + b ; partial colsum; diag sx.
  const float bb = *bp;
  float rxv[4], p[4] = {0.f, 0.f, 0.f, 0.f};
#pragma unroll
  for (int ni = 0; ni < 4; ++ni)
    rxv[ni] = rxn[j0 + wj * 64 + ni * 16 + (l & 15)];
  const bool diagblk = (nt == (jt >> 6));

#pragma unroll
  for (int mi = 0; mi < 8; ++mi) {
    float4 rr = *(const float4*)&rcn[n0 + wm * 128 + mi * 16 + ((l >> 4) << 2)];
    const float rc[4] = {rr.x, rr.y, rr.z, rr.w};
#pragma unroll
    for (int ni = 0; ni < 4; ++ni) {
      floatx4 a = acc[mi][ni];
#pragma unroll
      for (int q = 0; q < 4; ++q)
        p[ni] += __expf(a[q] * rc[q] * rxv[ni] + bb);
      if (diagblk) {
        const int jg = j0 + wj * 64 + ni * 16 + (l & 15);
#pragma unroll
        for (int q = 0; q < 4; ++q) {
          const int mg = n0 + wm * 128 + mi * 16 + ((l >> 4) << 2) + q;
          if (mg == (jg >> 6)) sdiag_dot[jg] = a[q];
        }
      }
    }
  }
#pragma unroll
  for (int ni = 0; ni < 4; ++ni) {
    p[ni] += __shfl_xor(p[ni], 16, 64);
    p[ni] += __shfl_xor(p[ni], 32, 64);
  }
  if (l < 16) {
    const int slot = nt * 2 + wm;
#pragma unroll
    for (int ni = 0; ni < 4; ++ni)
      colsum_part[(size_t)slot * 32768 + j0 + wj * 64 + ni * 16 + l] = p[ni];
  }
}

// ---- kD: per-sample loss from 4 colsum partials + diagonal dot -> block
// partials (no atomics, no pre-zero needed).
__global__ __launch_bounds__(256) void kD(const float* __restrict__ colsum_part,
    const float* __restrict__ sdiag_dot, const float* __restrict__ xx,
    const float* __restrict__ ss, const float* __restrict__ rcn,
    const float* __restrict__ wp, const float* __restrict__ bp,
    float* __restrict__ partial) {
  const int j = blockIdx.x * 256 + threadIdx.x;
  const int i = j >> 6;
  const float ww = *wp, bb = *bp;
  const float sx = sdiag_dot[j];
  const float xxv = xx[j];
  const float xn = fmaxf(sqrtf(xxv), EPS);
  const float rx = 1.0f / xn;
  const float sd = sx * rcn[i] * rx + bb;                         // S_diag
  const float exn = sqrtf(fmaxf(ss[i] - 2.f * sx + xxv, 0.f)) * (1.f / 63.f);
  const float edot = (sx - xxv) * (1.f / 63.f);
  const float sm = ww * edot / (fmaxf(exn, EPS) * xn) + bb;       // S_same
  const float cssum = colsum_part[j] + colsum_part[32768 + j]
                    + colsum_part[65536 + j] + colsum_part[98304 + j];
  const float tot = cssum - __expf(sd) + __expf(sm);
  float L = -sm + logf(fmaxf(tot, 1e-30f));
  for (int o = 32; o; o >>= 1) L += __shfl_xor(L, o, 64);
  __shared__ float red[4];
  if ((threadIdx.x & 63) == 0) red[threadIdx.x >> 6] = L;
  __syncthreads();
  if (threadIdx.x == 0)
    partial[blockIdx.x] = red[0] + red[1] + red[2] + red[3];
}

// ---- kE: reduce 128 block partials -> out (plain store, no atomic).
__global__ __launch_bounds__(128) void kE(const float* __restrict__ partial,
    float* __restrict__ out) {
  const int t = threadIdx.x;
  float v = partial[t];
  for (int o = 32; o; o >>= 1) v += __shfl_xor(v, o, 64);
  __shared__ float r2[2];
  if ((t & 63) == 0) r2[t >> 6] = v;
  __syncthreads();
  if (t == 0) out[0] = r2[0] + r2[1];
}

extern "C" void kernel_launch(void* const* d_in, const int* in_sizes, int n_in,
                              void* d_out, int out_size, void* d_ws, size_t ws_size,
                              hipStream_t stream) {
  const float* x  = (const float*)d_in[0];
  const float* wp = (const float*)d_in[1];
  const float* bp = (const float*)d_in[2];
  float* out = (float*)d_out;

  // ws layout (float offsets):
  float* fws = (float*)d_ws;
  float* ss          = fws;              // 512
  float* rcn         = fws + 512;        // 512
  float* xx          = fws + 1024;       // 32768
  float* rxn         = fws + 33792;      // 32768
  float* colsum_part = fws + 66560;      // 131072 (4 x 32768)
  float* sdiag_dot   = fws + 197632;     // 32768
  float* partial     = fws + 230400;     // 128
  float* sums_f32    = fws + 230528;     // 393216
  uchar_t* sums8fm   = (uchar_t*)(fws + 623744);  // 393216 bytes
  uchar_t* xbf8fm    = (uchar_t*)(fws + 722048);  // 25165824 bytes
  // total ~= 28.0 MiB; NO memsets needed (all buffers fully overwritten)

  kA<<<512, 256, 0, stream>>>(x, xbf8fm, sums_f32, ss, rcn, xx, rxn, wp);
  kA2<<<32, 256, 0, stream>>>(sums_f32, sums8fm);
  kC<<<256, 512, 0, stream>>>(xbf8fm, sums8fm, rcn, rxn, colsum_part, sdiag_dot, bp);
  kD<<<128, 256, 0, stream>>>(colsum_part, sdiag_dot, xx, ss, rcn, wp, bp, partial);
  kE<<<1, 128, 0, stream>>>(partial, out);
}